// Round 4
// baseline (34114.786 us; speedup 1.0000x reference)
//
#include <hip/hip_runtime.h>
#include <stdint.h>
#include <stddef.h>

#define B_ 64
#define T_ 128
#define S_ 128
#define H_ 1024
#define E_ 512
#define V_ 4000
#define VP_ 4032
#define XH_ 1536
#define BH_ (B_*H_)
#define NBLK 512

typedef __attribute__((ext_vector_type(8))) short bf16x8;
typedef __attribute__((ext_vector_type(4))) float f32x4;
typedef unsigned short u16;
typedef unsigned int u32;

__device__ __forceinline__ float bf2f(u16 x){
  union { unsigned int u; float f; } c; c.u = ((unsigned int)x) << 16; return c.f;
}
__device__ __forceinline__ u16 f2bf(float f){
  union { float f; unsigned int u; } c; c.f = f;
  return (u16)((c.u + 0x7FFFu + ((c.u >> 16) & 1u)) >> 16);
}
__device__ __forceinline__ void split2(float x, u16& hi, u16& lo){
  u16 h = f2bf(x); hi = h; lo = f2bf(x - bf2f(h));
}
__device__ __forceinline__ float sigm(float x){ return 1.f/(1.f+__expf(-x)); }
__device__ __forceinline__ float tanh_f(float x){
  float z = __expf(-2.f*fabsf(x));
  float r = (1.f - z)/(1.f + z);
  return x < 0.f ? -r : r;
}

// ---------------- prep kernels ----------------

__global__ __launch_bounds__(256) void k_f2bf(const float* __restrict__ in, u16* __restrict__ out, int n){
  int i = blockIdx.x*256 + threadIdx.x;
  if (i < n) out[i] = f2bf(in[i]);
}

__global__ __launch_bounds__(256) void k_split(const float* __restrict__ in,
                                               u16* __restrict__ hi, u16* __restrict__ lo, int n){
  int i = blockIdx.x*256 + threadIdx.x;
  if (i < n){ u16 a, b; split2(in[i], a, b); hi[i] = a; lo[i] = b; }
}

__global__ __launch_bounds__(256) void k_waT_split(const float* __restrict__ Wa,
                                                   u16* __restrict__ Th, u16* __restrict__ Tl){
  int n = blockIdx.x;
  for (int h = threadIdx.x; h < H_; h += 256){
    u16 a, b; split2(Wa[(size_t)h*H_ + n], a, b);
    Th[(size_t)n*H_ + h] = a; Tl[(size_t)n*H_ + h] = b;
  }
}

__global__ __launch_bounds__(256) void k_bias(const float* __restrict__ a, const float* __restrict__ b,
                                              float* __restrict__ o, int n){
  int i = blockIdx.x*256 + threadIdx.x;
  if (i < n) o[i] = a[i] + b[i];
}

__global__ __launch_bounds__(256) void k_emb(const int* __restrict__ tok, const float* __restrict__ emb,
                                             u16* __restrict__ ehi, u16* __restrict__ elo){
  int bid = blockIdx.x;
  int t = bid >> 6, b = bid & 63;
  int tk = tok[b*T_ + t];
  const float* src = emb + (size_t)tk*E_;
  u16* dh = ehi + (size_t)bid*E_;
  u16* dl = elo + (size_t)bid*E_;
  for (int j = threadIdx.x; j < E_; j += 256){
    if (tk == 0){ dh[j] = 0; dl[j] = 0; }
    else { u16 a, c; split2(src[j], a, c); dh[j] = a; dl[j] = c; }
  }
}

__global__ __launch_bounds__(256) void k_init(const float* __restrict__ h0, const float* __restrict__ c0,
                                              float* __restrict__ hs, float* __restrict__ cs,
                                              u16* __restrict__ h0h, u16* __restrict__ h0l,
                                              u16* __restrict__ h1h, u16* __restrict__ h1l,
                                              u32* __restrict__ bar){
  int i = blockIdx.x*256 + threadIdx.x;
  if (i < 2*BH_){ hs[i] = h0[i]; cs[i] = c0[i]; }
  if (i < BH_){
    u16 a, b;
    split2(h0[i], a, b);        h0h[i] = a; h0l[i] = b;
    split2(h0[BH_ + i], a, b);  h1h[i] = a; h1l[i] = b;
  }
  if (i < 2048) bar[i] = 0;   // barrier state reset every launch (replay-safe)
}

// encWa[r][n] = sum_h enc[r][h] * Wa[h][n]  (fp32 out via 3-pass hi/lo MFMA)
__global__ __launch_bounds__(256) void k_encWa(const u16* __restrict__ Ah, const u16* __restrict__ Al,
                                               const u16* __restrict__ Bh, const u16* __restrict__ Bl,
                                               float* __restrict__ out){
  int w = threadIdx.x >> 6, lane = threadIdx.x & 63;
  int lm = lane & 15, q = lane >> 4, qo = q*8;
  int m0 = blockIdx.x*64 + w*16;
  int n0 = blockIdx.y*64;
  const u16* arh = Ah + (size_t)(m0 + lm)*H_ + qo;
  const u16* arl = Al + (size_t)(m0 + lm)*H_ + qo;
  const u16* brh[4]; const u16* brl[4];
  #pragma unroll
  for (int nf = 0; nf < 4; nf++){
    brh[nf] = Bh + (size_t)(n0 + nf*16 + lm)*H_ + qo;
    brl[nf] = Bl + (size_t)(n0 + nf*16 + lm)*H_ + qo;
  }
  f32x4 acc[4] = {};
  for (int k = 0; k < H_; k += 32){
    bf16x8 ah = *(const bf16x8*)(arh + k);
    bf16x8 al = *(const bf16x8*)(arl + k);
    #pragma unroll
    for (int nf = 0; nf < 4; nf++){
      bf16x8 bh = *(const bf16x8*)(brh[nf] + k);
      bf16x8 bl = *(const bf16x8*)(brl[nf] + k);
      acc[nf] = __builtin_amdgcn_mfma_f32_16x16x32_bf16(ah, bh, acc[nf], 0, 0, 0);
      acc[nf] = __builtin_amdgcn_mfma_f32_16x16x32_bf16(al, bh, acc[nf], 0, 0, 0);
      acc[nf] = __builtin_amdgcn_mfma_f32_16x16x32_bf16(ah, bl, acc[nf], 0, 0, 0);
    }
  }
  #pragma unroll
  for (int nf = 0; nf < 4; nf++)
    #pragma unroll
    for (int r = 0; r < 4; r++)
      out[(size_t)(m0 + q*4 + r)*H_ + n0 + nf*16 + lm] = acc[nf][r];
}

// ---------------- grid barrier (two-level, sense via generation counter) ----------------

__device__ __forceinline__ void gridbar(u32* bb){
  __syncthreads();
  if (threadIdx.x == 0){
    __threadfence();
    u32* grp  = bb + (blockIdx.x & 31)*32;   // 32 groups x 16 blocks
    u32* root = bb + 1024;
    u32* gen  = bb + 1056;
    u32 g = __hip_atomic_load(gen, __ATOMIC_RELAXED, __HIP_MEMORY_SCOPE_AGENT);
    u32 a = __hip_atomic_fetch_add(grp, 1u, __ATOMIC_ACQ_REL, __HIP_MEMORY_SCOPE_AGENT);
    if (a == 15u){
      __hip_atomic_store(grp, 0u, __ATOMIC_RELAXED, __HIP_MEMORY_SCOPE_AGENT);
      u32 r = __hip_atomic_fetch_add(root, 1u, __ATOMIC_ACQ_REL, __HIP_MEMORY_SCOPE_AGENT);
      if (r == 31u){
        __hip_atomic_store(root, 0u, __ATOMIC_RELAXED, __HIP_MEMORY_SCOPE_AGENT);
        __hip_atomic_store(gen, g + 1u, __ATOMIC_RELEASE, __HIP_MEMORY_SCOPE_AGENT);
      } else {
        while (__hip_atomic_load(gen, __ATOMIC_RELAXED, __HIP_MEMORY_SCOPE_AGENT) == g)
          __builtin_amdgcn_s_sleep(2);
      }
    } else {
      while (__hip_atomic_load(gen, __ATOMIC_RELAXED, __HIP_MEMORY_SCOPE_AGENT) == g)
        __builtin_amdgcn_s_sleep(2);
    }
    __threadfence();
  }
  __syncthreads();
}

// ---------------- phases of the persistent step kernel ----------------

// scores[b][s] = h1[b] . encWa[b][s]   512 blocks = b(64) x so(8); 4 waves x 4 s
__device__ __forceinline__ void ph_score(const float* __restrict__ h1st, const float* __restrict__ encWa,
                                         float* __restrict__ scores, int bid, int tid){
  int b = bid >> 3, so = bid & 7;
  int w = tid >> 6, lane = tid & 63;
  const float* h1r = h1st + (size_t)b*H_ + lane*16;
  float hf[16];
  #pragma unroll
  for (int jj = 0; jj < 16; jj += 4){
    float4 v = *(const float4*)(h1r + jj);
    hf[jj] = v.x; hf[jj+1] = v.y; hf[jj+2] = v.z; hf[jj+3] = v.w;
  }
  #pragma unroll
  for (int si = 0; si < 4; si++){
    int s = so*16 + w*4 + si;
    const float* er = encWa + ((size_t)b*S_ + s)*H_ + lane*16;
    float acc = 0.f;
    #pragma unroll
    for (int jj = 0; jj < 16; jj += 4){
      float4 v = *(const float4*)(er + jj);
      acc += hf[jj]*v.x + hf[jj+1]*v.y + hf[jj+2]*v.z + hf[jj+3]*v.w;
    }
    #pragma unroll
    for (int off = 32; off; off >>= 1) acc += __shfl_xor(acc, off, 64);
    if (lane == 0) scores[b*S_ + s] = acc;
  }
}

// softmax (redundant per block) + 128-dim ctx slice.  512 blocks = b(64) x hs(8)
__device__ __forceinline__ void ph_ctx(const float* __restrict__ scores, const float* __restrict__ enc,
                                       u16* __restrict__ ctxh, u16* __restrict__ ctxl, int bid, int tid){
  int b = bid >> 3, hs = bid & 7;
  int sg = tid >> 6, lane = tid & 63;
  __shared__ float p[S_];
  __shared__ float cp[4][128];
  if (tid < S_) p[tid] = scores[b*S_ + tid];
  __syncthreads();
  float mx = -1e30f;
  #pragma unroll 8
  for (int s = 0; s < S_; s++) mx = fmaxf(mx, p[s]);
  __syncthreads();
  if (tid < S_) p[tid] = __expf(p[tid] - mx);
  __syncthreads();
  float sum = 0.f;
  #pragma unroll 8
  for (int s = 0; s < S_; s++) sum += p[s];
  float inv = 1.f/sum;
  int d0 = hs*128 + lane*2;
  const float* eb = enc + ((size_t)b*S_)*H_ + d0;
  float a0 = 0.f, a1 = 0.f;
  #pragma unroll 4
  for (int si = 0; si < 32; si++){
    int s = sg*32 + si;
    float pv = p[s];
    float2 ev = *(const float2*)(eb + (size_t)s*H_);
    a0 += pv*ev.x; a1 += pv*ev.y;
  }
  if (sg != 0){ cp[sg][lane*2] = a0; cp[sg][lane*2+1] = a1; }
  __syncthreads();
  if (sg == 0){
    #pragma unroll
    for (int gg = 1; gg < 4; gg++){ a0 += cp[gg][lane*2]; a1 += cp[gg][lane*2+1]; }
    int o = b*H_ + d0;
    u16 hh, hl;
    split2(a0*inv, hh, hl); ctxh[o]   = hh; ctxl[o]   = hl;
    split2(a1*inv, hh, hl); ctxh[o+1] = hh; ctxl[o+1] = hl;
  }
  __syncthreads();   // protect LDS before next phase reuses it
}

// K-sliced gate GEMM segment: acc[m] over k in [klo,khi) of x@W^T (hi/lo 3-pass)
__device__ __forceinline__ void seg_run(const u16* __restrict__ xh, const u16* __restrict__ xl, int sx,
                                        const u16* __restrict__ wh, const u16* __restrict__ wl,
                                        int lm, int qo, int klo, int khi, f32x4* acc){
  if (klo >= khi) return;
  #pragma unroll 2
  for (int k = klo; k < khi; k += 32){
    bf16x8 vbh = *(const bf16x8*)(wh + k + qo);
    bf16x8 vbl = *(const bf16x8*)(wl + k + qo);
    #pragma unroll
    for (int m = 0; m < 4; m++){
      const u16* axh = xh + (size_t)(m*16 + lm)*sx + k + qo;
      const u16* axl = xl + (size_t)(m*16 + lm)*sx + k + qo;
      bf16x8 vah = *(const bf16x8*)axh;
      bf16x8 val = *(const bf16x8*)axl;
      acc[m] = __builtin_amdgcn_mfma_f32_16x16x32_bf16(vah, vbh, acc[m], 0, 0, 0);
      acc[m] = __builtin_amdgcn_mfma_f32_16x16x32_bf16(val, vbh, acc[m], 0, 0, 0);
      acc[m] = __builtin_amdgcn_mfma_f32_16x16x32_bf16(vah, vbl, acc[m], 0, 0, 0);
    }
  }
}

// gates partial GEMM. 512 blocks = j(64) x kq(8); 4 waves = 4 gates; all 64 batch rows.
__device__ __forceinline__ void ph_gemm(
    const u16* __restrict__ x1h, const u16* __restrict__ x1l,
    const u16* __restrict__ W1h, const u16* __restrict__ W1l, int ld1, int sx1, int k1,
    const u16* __restrict__ x2h, const u16* __restrict__ x2l,
    const u16* __restrict__ W2h, const u16* __restrict__ W2l, int ld2, int sx2, int k2,
    const u16* __restrict__ x3h, const u16* __restrict__ x3l,
    const u16* __restrict__ W3h, const u16* __restrict__ W3l, int ld3, int sx3, int k3,
    int Ks, float* __restrict__ part, int bid, int tid){
  int j = bid & 63, kq = bid >> 6;
  int g = tid >> 6, lane = tid & 63;
  int lm = lane & 15, q = lane >> 4, qo = q*8;
  int n = g*H_ + j*16 + lm;
  int c0 = kq*Ks, c1 = c0 + Ks;
  f32x4 acc[4] = {};
  {
    int hi = (c1 < k1) ? c1 : k1;
    seg_run(x1h, x1l, sx1, W1h + (size_t)n*ld1, W1l + (size_t)n*ld1, lm, qo, c0, hi, acc);
  }
  {
    int lo = c0 - k1; if (lo < 0) lo = 0;
    int hi = c1 - k1; if (hi > k2) hi = k2;
    seg_run(x2h, x2l, sx2, W2h + (size_t)n*ld2, W2l + (size_t)n*ld2, lm, qo, lo, hi, acc);
  }
  if (k3 > 0){
    int lo = c0 - k1 - k2; if (lo < 0) lo = 0;
    int hi = c1 - k1 - k2; if (hi > k3) hi = k3;
    seg_run(x3h, x3l, sx3, W3h + (size_t)n*ld3, W3l + (size_t)n*ld3, lm, qo, lo, hi, acc);
  }
  #pragma unroll
  for (int m = 0; m < 4; m++)
    #pragma unroll
    for (int r = 0; r < 4; r++)
      part[((size_t)(kq*64 + m*16 + q*4 + r))*4096 + n] = acc[m][r];
}

// combine 8 K-partials + bias, LSTM cell update. 512 blocks x 128 active threads.
__device__ __forceinline__ void ph_cell(const float* __restrict__ part, const float* __restrict__ bias,
                                        float* __restrict__ cst, float* __restrict__ hst,
                                        u16* __restrict__ hnh, u16* __restrict__ hnl,
                                        u16* __restrict__ hall, int bid, int tid){
  if (tid < 128){
    int idx = bid*128 + tid;
    int d = idx & 1023, b = idx >> 10;
    float gs[4];
    #pragma unroll
    for (int g = 0; g < 4; g++){
      float s = bias[g*H_ + d];
      #pragma unroll
      for (int kq = 0; kq < 8; kq++)
        s += part[((size_t)(kq*64 + b))*4096 + (size_t)g*H_ + d];
      gs[g] = s;
    }
    size_t sidx = (size_t)b*H_ + d;
    float cn = sigm(gs[1])*cst[sidx] + sigm(gs[0])*tanh_f(gs[2]);
    float hn = sigm(gs[3])*tanh_f(cn);
    cst[sidx] = cn; hst[sidx] = hn;
    u16 hh, hl; split2(hn, hh, hl);
    hnh[sidx] = hh; hnl[sidx] = hl;
    if (hall) hall[sidx] = hh;
  }
}

// ---------------- the persistent step kernel ----------------

struct PArgs {
  const float* encWa; const float* enc;
  const u16 *e_hi, *e_lo;
  const u16 *Wih0_hi, *Wih0_lo, *Whh0_hi, *Whh0_lo;
  const u16 *Wih1_hi, *Wih1_lo, *Whh1_hi, *Whh1_lo;
  const float *bias0, *bias1;
  float *hst, *cst;
  u16 *h0Ah, *h0Al, *h0Bh, *h0Bl, *h1Ah, *h1Al, *h1Bh, *h1Bl;
  u16 *ctxh, *ctxl;
  float *scores, *part;
  u16 *h1all;
  u32 *bar;
};

__global__ __launch_bounds__(256, 2) void k_steps(PArgs A){
  int bid = blockIdx.x, tid = threadIdx.x;
  for (int t = 0; t < T_; t++){
    const u16* h0ph = (t & 1) ? A.h0Bh : A.h0Ah;  const u16* h0pl = (t & 1) ? A.h0Bl : A.h0Al;
    u16* h0nh = (t & 1) ? A.h0Ah : A.h0Bh;        u16* h0nl = (t & 1) ? A.h0Al : A.h0Bl;
    const u16* h1ph = (t & 1) ? A.h1Bh : A.h1Ah;  const u16* h1pl = (t & 1) ? A.h1Bl : A.h1Al;
    u16* h1nh = (t & 1) ? A.h1Ah : A.h1Bh;        u16* h1nl = (t & 1) ? A.h1Al : A.h1Bl;

    ph_score(A.hst + BH_, A.encWa, A.scores, bid, tid);
    gridbar(A.bar);
    ph_ctx(A.scores, A.enc, A.ctxh, A.ctxl, bid, tid);
    gridbar(A.bar);
    ph_gemm(A.e_hi + (size_t)t*B_*E_, A.e_lo + (size_t)t*B_*E_, A.Wih0_hi, A.Wih0_lo, XH_, E_, E_,
            A.ctxh, A.ctxl, A.Wih0_hi + E_, A.Wih0_lo + E_, XH_, H_, H_,
            h0ph, h0pl, A.Whh0_hi, A.Whh0_lo, H_, H_, H_,
            320, A.part, bid, tid);
    gridbar(A.bar);
    ph_cell(A.part, A.bias0, A.cst, A.hst, h0nh, h0nl, (u16*)nullptr, bid, tid);
    gridbar(A.bar);
    ph_gemm(h0nh, h0nl, A.Wih1_hi, A.Wih1_lo, H_, H_, H_,
            h1ph, h1pl, A.Whh1_hi, A.Whh1_lo, H_, H_, H_,
            (const u16*)nullptr, (const u16*)nullptr, (const u16*)nullptr, (const u16*)nullptr, 0, 0, 0,
            256, A.part, bid, tid);
    gridbar(A.bar);
    ph_cell(A.part, A.bias1, A.cst + BH_, A.hst + BH_, h1nh, h1nl, A.h1all + (size_t)t*BH_, bid, tid);
    gridbar(A.bar);
  }
}

// ---------------- final projection + state copy ----------------

__global__ __launch_bounds__(256) void k_proj(const u16* __restrict__ h1all, const u16* __restrict__ Wp,
                                              const float* __restrict__ pb, float* __restrict__ out){
  int w = threadIdx.x >> 6, lane = threadIdx.x & 63;
  int lm = lane & 15, q = lane >> 4, qo = q*8;
  int m0 = blockIdx.x*64 + w*16;
  int n0 = blockIdx.y*64;
  const u16* arow = h1all + (size_t)(m0 + lm)*H_ + qo;
  const u16* brow[4];
  #pragma unroll
  for (int nf = 0; nf < 4; nf++) brow[nf] = Wp + (size_t)(n0 + nf*16 + lm)*H_ + qo;
  f32x4 acc[4] = {};
  for (int k = 0; k < H_; k += 32){
    bf16x8 a = *(const bf16x8*)(arow + k);
    #pragma unroll
    for (int nf = 0; nf < 4; nf++){
      bf16x8 bb = *(const bf16x8*)(brow[nf] + k);
      acc[nf] = __builtin_amdgcn_mfma_f32_16x16x32_bf16(a, bb, acc[nf], 0, 0, 0);
    }
  }
  #pragma unroll
  for (int nf = 0; nf < 4; nf++){
    int v = n0 + nf*16 + lm;
    if (v >= V_) continue;
    float bias = pb[v];
    #pragma unroll
    for (int r = 0; r < 4; r++){
      int row = m0 + q*4 + r;           // row = t*64 + b
      int t = row >> 6, b = row & 63;
      out[((size_t)b*T_ + t)*V_ + v] = acc[nf][r] + bias;
    }
  }
}

__global__ __launch_bounds__(256) void k_final(const float* __restrict__ hs, const float* __restrict__ cs,
                                               float* __restrict__ out){
  size_t LOG = (size_t)B_*T_*V_;
  int i = blockIdx.x*256 + threadIdx.x;
  if (i < 2*BH_){
    out[LOG + i] = hs[i];
    out[LOG + 2*BH_ + i] = cs[i];
  }
}

// ---------------- launch ----------------

extern "C" void kernel_launch(void* const* d_in, const int* in_sizes, int n_in,
                              void* d_out, int out_size, void* d_ws, size_t ws_size,
                              hipStream_t stream){
  (void)in_sizes; (void)n_in; (void)out_size; (void)ws_size;
  const int*   dec  = (const int*)  d_in[0];
  const float* enc  = (const float*)d_in[1];
  const float* h0i_ = (const float*)d_in[3];
  const float* c0i_ = (const float*)d_in[4];
  const float* emb  = (const float*)d_in[5];
  const float* Wa   = (const float*)d_in[6];
  const float* Wih0 = (const float*)d_in[7];
  const float* Whh0 = (const float*)d_in[8];
  const float* bih0 = (const float*)d_in[9];
  const float* bhh0 = (const float*)d_in[10];
  const float* Wih1 = (const float*)d_in[11];
  const float* Whh1 = (const float*)d_in[12];
  const float* bih1 = (const float*)d_in[13];
  const float* bhh1 = (const float*)d_in[14];
  const float* pW   = (const float*)d_in[15];
  const float* pb   = (const float*)d_in[16];
  float* out = (float*)d_out;

  // Scratch carved from the dead logits region of d_out (125 MiB, overwritten by k_proj at end).
  char* db = (char*)d_out;
  float* encWa  = (float*)(db);                    // 33,554,432 B
  u16* e_hi     = (u16*)(db + 33554432);           //  8,388,608
  u16* e_lo     = (u16*)(db + 41943040);           //  8,388,608 -> 50,331,648
  // transient (dead after k_encWa, then overwritten by weight splits):
  u16* enc_hi   = (u16*)(db + 50331648);           // 16,777,216 -> 67,108,864
  u16* enc_lo   = (u16*)(db + 67108864);           // 16,777,216 -> 83,886,080
  // weights (written AFTER k_encWa completes; stream-ordered):
  u16* Wih0_hi  = (u16*)(db + 50331648);
  u16* Wih0_lo  = (u16*)(db + 62914560);
  u16* Whh0_hi  = (u16*)(db + 75497472);
  u16* Whh0_lo  = (u16*)(db + 83886080);
  u16* Wih1_hi  = (u16*)(db + 92274688);
  u16* Wih1_lo  = (u16*)(db + 100663296);
  u16* Whh1_hi  = (u16*)(db + 109051904);
  u16* Whh1_lo  = (u16*)(db + 117440512);          // -> 125,829,120 (<131,072,000)

  char* ws = (char*)d_ws;
  size_t off = 0;
  auto alloc = [&](size_t bytes)->void*{ void* p = ws + off; off = (off + bytes + 255) & ~(size_t)255; return p; };
  u16* WaT_hi  = (u16*)alloc((size_t)H_*H_*2);
  u16* WaT_lo  = (u16*)alloc((size_t)H_*H_*2);
  u16* pW_bf   = (u16*)alloc((size_t)VP_*H_*2);
  u16* h1all   = (u16*)alloc((size_t)T_*B_*H_*2);
  float* hst   = (float*)alloc((size_t)2*BH_*4);
  float* cst   = (float*)alloc((size_t)2*BH_*4);
  u16* h0Ah = (u16*)alloc((size_t)BH_*2);  u16* h0Al = (u16*)alloc((size_t)BH_*2);
  u16* h0Bh = (u16*)alloc((size_t)BH_*2);  u16* h0Bl = (u16*)alloc((size_t)BH_*2);
  u16* h1Ah = (u16*)alloc((size_t)BH_*2);  u16* h1Al = (u16*)alloc((size_t)BH_*2);
  u16* h1Bh = (u16*)alloc((size_t)BH_*2);  u16* h1Bl = (u16*)alloc((size_t)BH_*2);
  u16* ctxh = (u16*)alloc((size_t)BH_*2);  u16* ctxl = (u16*)alloc((size_t)BH_*2);
  float* bias0 = (float*)alloc(4096*4);
  float* bias1 = (float*)alloc(4096*4);
  float* scores = (float*)alloc((size_t)B_*S_*4);
  float* part  = (float*)alloc((size_t)8*64*4096*4);   // 8 MB
  u32* bar     = (u32*)alloc(2048*4);

  auto split = [&](const float* src, u16* hi, u16* lo, int n){
    k_split<<<(n + 255)/256, 256, 0, stream>>>(src, hi, lo, n);
  };

  // phase 1: enc split + Wa^T split + encWa (fp32)
  split(enc, enc_hi, enc_lo, B_*S_*H_);
  k_waT_split<<<H_, 256, 0, stream>>>(Wa, WaT_hi, WaT_lo);
  k_encWa<<<dim3(128, 16), 256, 0, stream>>>(enc_hi, enc_lo, WaT_hi, WaT_lo, encWa);

  // phase 2: weight splits (overwrite enc_hi/enc_lo region)
  split(Wih0, Wih0_hi, Wih0_lo, 4*H_*XH_);
  split(Whh0, Whh0_hi, Whh0_lo, 4*H_*H_);
  split(Wih1, Wih1_hi, Wih1_lo, 4*H_*H_);
  split(Whh1, Whh1_hi, Whh1_lo, 4*H_*H_);
  hipMemsetAsync(pW_bf + (size_t)V_*H_, 0, (size_t)(VP_ - V_)*H_*2, stream);
  k_f2bf<<<(V_*H_ + 255)/256, 256, 0, stream>>>(pW, pW_bf, V_*H_);
  k_bias<<<16, 256, 0, stream>>>(bih0, bhh0, bias0, 4096);
  k_bias<<<16, 256, 0, stream>>>(bih1, bhh1, bias1, 4096);
  k_emb<<<T_*B_, 256, 0, stream>>>(dec, emb, e_hi, e_lo);
  k_init<<<(2*BH_ + 255)/256, 256, 0, stream>>>(h0i_, c0i_, hst, cst, h0Ah, h0Al, h1Ah, h1Al, bar);

  // phase 3: persistent kernel runs all 128 decode steps with grid barriers
  PArgs A;
  A.encWa = encWa; A.enc = enc;
  A.e_hi = e_hi; A.e_lo = e_lo;
  A.Wih0_hi = Wih0_hi; A.Wih0_lo = Wih0_lo; A.Whh0_hi = Whh0_hi; A.Whh0_lo = Whh0_lo;
  A.Wih1_hi = Wih1_hi; A.Wih1_lo = Wih1_lo; A.Whh1_hi = Whh1_hi; A.Whh1_lo = Whh1_lo;
  A.bias0 = bias0; A.bias1 = bias1;
  A.hst = hst; A.cst = cst;
  A.h0Ah = h0Ah; A.h0Al = h0Al; A.h0Bh = h0Bh; A.h0Bl = h0Bl;
  A.h1Ah = h1Ah; A.h1Al = h1Al; A.h1Bh = h1Bh; A.h1Bl = h1Bl;
  A.ctxh = ctxh; A.ctxl = ctxl;
  A.scores = scores; A.part = part; A.h1all = h1all; A.bar = bar;
  k_steps<<<NBLK, 256, 0, stream>>>(A);

  // phase 4: deferred projection over all 128 steps + final states
  k_proj<<<dim3(128, VP_/64), 256, 0, stream>>>(h1all, pW_bf, pb, out);
  k_final<<<(2*BH_ + 255)/256, 256, 0, stream>>>(hst, cst, out);
}

// Round 5
// 10469.500 us; speedup vs baseline: 3.2585x; 3.2585x over previous
//
#include <hip/hip_runtime.h>
#include <stdint.h>
#include <stddef.h>

#define B_ 64
#define T_ 128
#define S_ 128
#define H_ 1024
#define E_ 512
#define V_ 4000
#define VP_ 4032
#define XH_ 1536
#define BH_ (B_*H_)

typedef __attribute__((ext_vector_type(8))) short bf16x8;
typedef __attribute__((ext_vector_type(4))) float f32x4;
typedef unsigned short u16;

__device__ __forceinline__ float bf2f(u16 x){
  union { unsigned int u; float f; } c; c.u = ((unsigned int)x) << 16; return c.f;
}
__device__ __forceinline__ u16 f2bf(float f){
  union { float f; unsigned int u; } c; c.f = f;
  return (u16)((c.u + 0x7FFFu + ((c.u >> 16) & 1u)) >> 16);
}
__device__ __forceinline__ void split2(float x, u16& hi, u16& lo){
  u16 h = f2bf(x); hi = h; lo = f2bf(x - bf2f(h));
}
__device__ __forceinline__ float sigm(float x){ return 1.f/(1.f+__expf(-x)); }
__device__ __forceinline__ float tanh_f(float x){
  float z = __expf(-2.f*fabsf(x));
  float r = (1.f - z)/(1.f + z);
  return x < 0.f ? -r : r;
}

// ---------------- prep kernels ----------------

__global__ __launch_bounds__(256) void k_f2bf(const float* __restrict__ in, u16* __restrict__ out, int n){
  int i = blockIdx.x*256 + threadIdx.x;
  if (i < n) out[i] = f2bf(in[i]);
}

__global__ __launch_bounds__(256) void k_split(const float* __restrict__ in,
                                               u16* __restrict__ hi, u16* __restrict__ lo, int n){
  int i = blockIdx.x*256 + threadIdx.x;
  if (i < n){ u16 a, b; split2(in[i], a, b); hi[i] = a; lo[i] = b; }
}

__global__ __launch_bounds__(256) void k_waT_split(const float* __restrict__ Wa,
                                                   u16* __restrict__ Th, u16* __restrict__ Tl){
  int n = blockIdx.x;
  for (int h = threadIdx.x; h < H_; h += 256){
    u16 a, b; split2(Wa[(size_t)h*H_ + n], a, b);
    Th[(size_t)n*H_ + h] = a; Tl[(size_t)n*H_ + h] = b;
  }
}

__global__ __launch_bounds__(256) void k_bias(const float* __restrict__ a, const float* __restrict__ b,
                                              float* __restrict__ o, int n){
  int i = blockIdx.x*256 + threadIdx.x;
  if (i < n) o[i] = a[i] + b[i];
}

__global__ __launch_bounds__(256) void k_emb(const int* __restrict__ tok, const float* __restrict__ emb,
                                             u16* __restrict__ ehi, u16* __restrict__ elo){
  int bid = blockIdx.x;
  int t = bid >> 6, b = bid & 63;
  int tk = tok[b*T_ + t];
  const float* src = emb + (size_t)tk*E_;
  u16* dh = ehi + (size_t)bid*E_;
  u16* dl = elo + (size_t)bid*E_;
  for (int j = threadIdx.x; j < E_; j += 256){
    if (tk == 0){ dh[j] = 0; dl[j] = 0; }
    else { u16 a, c; split2(src[j], a, c); dh[j] = a; dl[j] = c; }
  }
}

__global__ __launch_bounds__(256) void k_init(const float* __restrict__ h0, const float* __restrict__ c0,
                                              float* __restrict__ hs, float* __restrict__ cs,
                                              u16* __restrict__ h0h, u16* __restrict__ h0l,
                                              u16* __restrict__ h1h, u16* __restrict__ h1l){
  int i = blockIdx.x*256 + threadIdx.x;
  if (i < 2*BH_){ hs[i] = h0[i]; cs[i] = c0[i]; }
  if (i < BH_){
    u16 a, b;
    split2(h0[i], a, b);        h0h[i] = a; h0l[i] = b;
    split2(h0[BH_ + i], a, b);  h1h[i] = a; h1l[i] = b;
  }
}

// encWa[r][n] = sum_h enc[r][h] * Wa[h][n]  (fp32 out via 3-pass hi/lo MFMA)
__global__ __launch_bounds__(256) void k_encWa(const u16* __restrict__ Ah, const u16* __restrict__ Al,
                                               const u16* __restrict__ Bh, const u16* __restrict__ Bl,
                                               float* __restrict__ out){
  int w = threadIdx.x >> 6, lane = threadIdx.x & 63;
  int lm = lane & 15, q = lane >> 4, qo = q*8;
  int m0 = blockIdx.x*64 + w*16;
  int n0 = blockIdx.y*64;
  const u16* arh = Ah + (size_t)(m0 + lm)*H_ + qo;
  const u16* arl = Al + (size_t)(m0 + lm)*H_ + qo;
  const u16* brh[4]; const u16* brl[4];
  #pragma unroll
  for (int nf = 0; nf < 4; nf++){
    brh[nf] = Bh + (size_t)(n0 + nf*16 + lm)*H_ + qo;
    brl[nf] = Bl + (size_t)(n0 + nf*16 + lm)*H_ + qo;
  }
  f32x4 acc[4] = {};
  for (int k = 0; k < H_; k += 32){
    bf16x8 ah = *(const bf16x8*)(arh + k);
    bf16x8 al = *(const bf16x8*)(arl + k);
    #pragma unroll
    for (int nf = 0; nf < 4; nf++){
      bf16x8 bh = *(const bf16x8*)(brh[nf] + k);
      bf16x8 bl = *(const bf16x8*)(brl[nf] + k);
      acc[nf] = __builtin_amdgcn_mfma_f32_16x16x32_bf16(ah, bh, acc[nf], 0, 0, 0);
      acc[nf] = __builtin_amdgcn_mfma_f32_16x16x32_bf16(al, bh, acc[nf], 0, 0, 0);
      acc[nf] = __builtin_amdgcn_mfma_f32_16x16x32_bf16(ah, bl, acc[nf], 0, 0, 0);
    }
  }
  #pragma unroll
  for (int nf = 0; nf < 4; nf++)
    #pragma unroll
    for (int r = 0; r < 4; r++)
      out[(size_t)(m0 + q*4 + r)*H_ + n0 + nf*16 + lm] = acc[nf][r];
}

// ---------------- per-step kernels ----------------

// scores[b][s] = h1[b] . encWa[b][s]   grid 512 = b(64) x so(8); 8 waves x 2 s each
__global__ __launch_bounds__(512) void k_score(const float* __restrict__ h1st, const float* __restrict__ encWa,
                                               float* __restrict__ scores){
  int b = blockIdx.x >> 3, so = blockIdx.x & 7;
  int w = threadIdx.x >> 6, lane = threadIdx.x & 63;
  const float* h1r = h1st + (size_t)b*H_ + lane*16;
  float hf[16];
  #pragma unroll
  for (int jj = 0; jj < 16; jj += 4){
    float4 v = *(const float4*)(h1r + jj);
    hf[jj] = v.x; hf[jj+1] = v.y; hf[jj+2] = v.z; hf[jj+3] = v.w;
  }
  #pragma unroll
  for (int si = 0; si < 2; si++){
    int s = so*16 + w*2 + si;
    const float* er = encWa + ((size_t)b*S_ + s)*H_ + lane*16;
    float acc = 0.f;
    #pragma unroll
    for (int jj = 0; jj < 16; jj += 4){
      float4 v = *(const float4*)(er + jj);
      acc += hf[jj]*v.x + hf[jj+1]*v.y + hf[jj+2]*v.z + hf[jj+3]*v.w;
    }
    #pragma unroll
    for (int off = 32; off; off >>= 1) acc += __shfl_xor(acc, off, 64);
    if (lane == 0) scores[b*S_ + s] = acc;
  }
}

// softmax (redundant per block) + 128-dim ctx slice.  grid 512 = b(64) x hs(8); 8 s-groups
__global__ __launch_bounds__(512) void k_ctx(const float* __restrict__ scores, const float* __restrict__ enc,
                                             u16* __restrict__ ctxh, u16* __restrict__ ctxl){
  int b = blockIdx.x >> 3, hs = blockIdx.x & 7;
  int tid = threadIdx.x, sg = tid >> 6, lane = tid & 63;
  __shared__ float p[S_];
  __shared__ float cp[8][128];
  if (tid < S_) p[tid] = scores[b*S_ + tid];
  __syncthreads();
  float mx = -1e30f;
  #pragma unroll 8
  for (int s = 0; s < S_; s++) mx = fmaxf(mx, p[s]);
  __syncthreads();
  if (tid < S_) p[tid] = __expf(p[tid] - mx);
  __syncthreads();
  float sum = 0.f;
  #pragma unroll 8
  for (int s = 0; s < S_; s++) sum += p[s];
  float inv = 1.f/sum;
  int d0 = hs*128 + lane*2;
  const float* eb = enc + ((size_t)b*S_)*H_ + d0;
  float a0 = 0.f, a1 = 0.f;
  #pragma unroll 8
  for (int si = 0; si < 16; si++){
    int s = sg*16 + si;
    float pv = p[s];
    float2 ev = *(const float2*)(eb + (size_t)s*H_);
    a0 += pv*ev.x; a1 += pv*ev.y;
  }
  if (sg != 0){ cp[sg][lane*2] = a0; cp[sg][lane*2+1] = a1; }
  __syncthreads();
  if (sg == 0){
    #pragma unroll
    for (int gg = 1; gg < 8; gg++){ a0 += cp[gg][lane*2]; a1 += cp[gg][lane*2+1]; }
    int o = b*H_ + d0;
    u16 hh, hl;
    split2(a0*inv, hh, hl); ctxh[o]   = hh; ctxl[o]   = hl;
    split2(a1*inv, hh, hl); ctxh[o+1] = hh; ctxl[o+1] = hl;
  }
}

// K-sliced gate GEMM segment: acc[m] over k in [klo,khi) of x@W^T (hi/lo 3-pass)
__device__ __forceinline__ void seg_run(const u16* __restrict__ xh, const u16* __restrict__ xl, int sx,
                                        const u16* __restrict__ wh, const u16* __restrict__ wl,
                                        int lm, int qo, int klo, int khi, f32x4* acc){
  if (klo >= khi) return;
  #pragma unroll 4
  for (int k = klo; k < khi; k += 32){
    bf16x8 vbh = *(const bf16x8*)(wh + k + qo);
    bf16x8 vbl = *(const bf16x8*)(wl + k + qo);
    #pragma unroll
    for (int m = 0; m < 4; m++){
      const u16* axh = xh + (size_t)(m*16 + lm)*sx + k + qo;
      const u16* axl = xl + (size_t)(m*16 + lm)*sx + k + qo;
      bf16x8 vah = *(const bf16x8*)axh;
      bf16x8 val = *(const bf16x8*)axl;
      acc[m] = __builtin_amdgcn_mfma_f32_16x16x32_bf16(vah, vbh, acc[m], 0, 0, 0);
      acc[m] = __builtin_amdgcn_mfma_f32_16x16x32_bf16(val, vbh, acc[m], 0, 0, 0);
      acc[m] = __builtin_amdgcn_mfma_f32_16x16x32_bf16(vah, vbl, acc[m], 0, 0, 0);
    }
  }
}

// gates partial GEMM. grid 512 = j(64) x kq(8); 8 waves = 4 gates x 2 K-halves;
// halves combined through LDS; all 64 batch rows per wave.
// part[kq][batch][n] fp32, n = g*H + j*16 + lm
__global__ __launch_bounds__(512, 4) void k_gemm(
    const u16* __restrict__ x1h, const u16* __restrict__ x1l,
    const u16* __restrict__ W1h, const u16* __restrict__ W1l, int ld1, int sx1, int k1,
    const u16* __restrict__ x2h, const u16* __restrict__ x2l,
    const u16* __restrict__ W2h, const u16* __restrict__ W2l, int ld2, int sx2, int k2,
    const u16* __restrict__ x3h, const u16* __restrict__ x3l,
    const u16* __restrict__ W3h, const u16* __restrict__ W3l, int ld3, int sx3, int k3,
    int Ks, float* __restrict__ part){
  int j = blockIdx.x & 63, kq = blockIdx.x >> 6;
  int w = threadIdx.x >> 6;
  int g = w & 3, kh = w >> 2;
  int lane = threadIdx.x & 63;
  int lm = lane & 15, q = lane >> 4, qo = q*8;
  int n = g*H_ + j*16 + lm;
  int half = Ks >> 1;
  int c0 = kq*Ks + kh*half, c1 = c0 + half;
  f32x4 acc[4] = {};
  {
    int hi = (c1 < k1) ? c1 : k1;
    seg_run(x1h, x1l, sx1, W1h + (size_t)n*ld1, W1l + (size_t)n*ld1, lm, qo, c0, hi, acc);
  }
  {
    int lo = c0 - k1; if (lo < 0) lo = 0;
    int hi = c1 - k1; if (hi > k2) hi = k2;
    seg_run(x2h, x2l, sx2, W2h + (size_t)n*ld2, W2l + (size_t)n*ld2, lm, qo, lo, hi, acc);
  }
  if (k3 > 0){
    int lo = c0 - k1 - k2; if (lo < 0) lo = 0;
    int hi = c1 - k1 - k2; if (hi > k3) hi = k3;
    seg_run(x3h, x3l, sx3, W3h + (size_t)n*ld3, W3l + (size_t)n*ld3, lm, qo, lo, hi, acc);
  }
  __shared__ float smg[4][64][16];
  if (kh == 1){
    #pragma unroll
    for (int m = 0; m < 4; m++)
      #pragma unroll
      for (int r = 0; r < 4; r++)
        smg[g][m*16 + q*4 + r][lm] = acc[m][r];
  }
  __syncthreads();
  if (kh == 0){
    #pragma unroll
    for (int m = 0; m < 4; m++)
      #pragma unroll
      for (int r = 0; r < 4; r++)
        part[((size_t)(kq*64 + m*16 + q*4 + r))*4096 + n] = acc[m][r] + smg[g][m*16 + q*4 + r][lm];
  }
}

// combine 8 K-partials + bias, LSTM cell update. grid 512 x 128thr, thread=(b,d) d-fastest
__global__ __launch_bounds__(128) void k_cell(const float* __restrict__ part, const float* __restrict__ bias,
                                              float* __restrict__ cst, float* __restrict__ hst,
                                              u16* __restrict__ hnh, u16* __restrict__ hnl,
                                              u16* __restrict__ hall){
  int idx = blockIdx.x*128 + threadIdx.x;
  int d = idx & 1023, b = idx >> 10;
  float gs[4];
  #pragma unroll
  for (int g = 0; g < 4; g++){
    float s = bias[g*H_ + d];
    #pragma unroll
    for (int kq = 0; kq < 8; kq++)
      s += part[((size_t)(kq*64 + b))*4096 + (size_t)g*H_ + d];
    gs[g] = s;
  }
  size_t sidx = (size_t)b*H_ + d;
  float cn = sigm(gs[1])*cst[sidx] + sigm(gs[0])*tanh_f(gs[2]);
  float hn = sigm(gs[3])*tanh_f(cn);
  cst[sidx] = cn; hst[sidx] = hn;
  u16 hh, hl; split2(hn, hh, hl);
  hnh[sidx] = hh; hnl[sidx] = hl;
  if (hall) hall[sidx] = hh;
}

// ---------------- final projection + state copy ----------------

__global__ __launch_bounds__(256) void k_proj(const u16* __restrict__ h1all, const u16* __restrict__ Wp,
                                              const float* __restrict__ pb, float* __restrict__ out){
  int w = threadIdx.x >> 6, lane = threadIdx.x & 63;
  int lm = lane & 15, q = lane >> 4, qo = q*8;
  int m0 = blockIdx.x*64 + w*16;
  int n0 = blockIdx.y*64;
  const u16* arow = h1all + (size_t)(m0 + lm)*H_ + qo;
  const u16* brow[4];
  #pragma unroll
  for (int nf = 0; nf < 4; nf++) brow[nf] = Wp + (size_t)(n0 + nf*16 + lm)*H_ + qo;
  f32x4 acc[4] = {};
  for (int k = 0; k < H_; k += 32){
    bf16x8 a = *(const bf16x8*)(arow + k);
    #pragma unroll
    for (int nf = 0; nf < 4; nf++){
      bf16x8 bb = *(const bf16x8*)(brow[nf] + k);
      acc[nf] = __builtin_amdgcn_mfma_f32_16x16x32_bf16(a, bb, acc[nf], 0, 0, 0);
    }
  }
  #pragma unroll
  for (int nf = 0; nf < 4; nf++){
    int v = n0 + nf*16 + lm;
    if (v >= V_) continue;
    float bias = pb[v];
    #pragma unroll
    for (int r = 0; r < 4; r++){
      int row = m0 + q*4 + r;           // row = t*64 + b
      int t = row >> 6, b = row & 63;
      out[((size_t)b*T_ + t)*V_ + v] = acc[nf][r] + bias;
    }
  }
}

__global__ __launch_bounds__(256) void k_final(const float* __restrict__ hs, const float* __restrict__ cs,
                                               float* __restrict__ out){
  size_t LOG = (size_t)B_*T_*V_;
  int i = blockIdx.x*256 + threadIdx.x;
  if (i < 2*BH_){
    out[LOG + i] = hs[i];
    out[LOG + 2*BH_ + i] = cs[i];
  }
}

// ---------------- launch ----------------

extern "C" void kernel_launch(void* const* d_in, const int* in_sizes, int n_in,
                              void* d_out, int out_size, void* d_ws, size_t ws_size,
                              hipStream_t stream){
  (void)in_sizes; (void)n_in; (void)out_size; (void)ws_size;
  const int*   dec  = (const int*)  d_in[0];
  const float* enc  = (const float*)d_in[1];
  const float* h0i_ = (const float*)d_in[3];
  const float* c0i_ = (const float*)d_in[4];
  const float* emb  = (const float*)d_in[5];
  const float* Wa   = (const float*)d_in[6];
  const float* Wih0 = (const float*)d_in[7];
  const float* Whh0 = (const float*)d_in[8];
  const float* bih0 = (const float*)d_in[9];
  const float* bhh0 = (const float*)d_in[10];
  const float* Wih1 = (const float*)d_in[11];
  const float* Whh1 = (const float*)d_in[12];
  const float* bih1 = (const float*)d_in[13];
  const float* bhh1 = (const float*)d_in[14];
  const float* pW   = (const float*)d_in[15];
  const float* pb   = (const float*)d_in[16];
  float* out = (float*)d_out;

  // Scratch carved from the dead logits region of d_out (125 MiB, overwritten by k_proj at end).
  char* db = (char*)d_out;
  float* encWa  = (float*)(db);                    // 33,554,432 B
  u16* e_hi     = (u16*)(db + 33554432);           //  8,388,608
  u16* e_lo     = (u16*)(db + 41943040);           //  8,388,608 -> 50,331,648
  // transient (dead after k_encWa, then overwritten by weight splits):
  u16* enc_hi   = (u16*)(db + 50331648);           // 16,777,216 -> 67,108,864
  u16* enc_lo   = (u16*)(db + 67108864);           // 16,777,216 -> 83,886,080
  // weights (written AFTER k_encWa completes; stream-ordered):
  u16* Wih0_hi  = (u16*)(db + 50331648);
  u16* Wih0_lo  = (u16*)(db + 62914560);
  u16* Whh0_hi  = (u16*)(db + 75497472);
  u16* Whh0_lo  = (u16*)(db + 83886080);
  u16* Wih1_hi  = (u16*)(db + 92274688);
  u16* Wih1_lo  = (u16*)(db + 100663296);
  u16* Whh1_hi  = (u16*)(db + 109051904);
  u16* Whh1_lo  = (u16*)(db + 117440512);          // -> 125,829,120 (<131,072,000)

  char* ws = (char*)d_ws;
  size_t off = 0;
  auto alloc = [&](size_t bytes)->void*{ void* p = ws + off; off = (off + bytes + 255) & ~(size_t)255; return p; };
  u16* WaT_hi  = (u16*)alloc((size_t)H_*H_*2);
  u16* WaT_lo  = (u16*)alloc((size_t)H_*H_*2);
  u16* pW_bf   = (u16*)alloc((size_t)VP_*H_*2);
  u16* h1all   = (u16*)alloc((size_t)T_*B_*H_*2);
  float* hst   = (float*)alloc((size_t)2*BH_*4);
  float* cst   = (float*)alloc((size_t)2*BH_*4);
  u16* h0Ah = (u16*)alloc((size_t)BH_*2);  u16* h0Al = (u16*)alloc((size_t)BH_*2);
  u16* h0Bh = (u16*)alloc((size_t)BH_*2);  u16* h0Bl = (u16*)alloc((size_t)BH_*2);
  u16* h1Ah = (u16*)alloc((size_t)BH_*2);  u16* h1Al = (u16*)alloc((size_t)BH_*2);
  u16* h1Bh = (u16*)alloc((size_t)BH_*2);  u16* h1Bl = (u16*)alloc((size_t)BH_*2);
  u16* ctxh = (u16*)alloc((size_t)BH_*2);  u16* ctxl = (u16*)alloc((size_t)BH_*2);
  float* bias0 = (float*)alloc(4096*4);
  float* bias1 = (float*)alloc(4096*4);
  float* scores = (float*)alloc((size_t)B_*S_*4);
  float* part  = (float*)alloc((size_t)8*64*4096*4);   // 8 MB, shared by both layers

  auto split = [&](const float* src, u16* hi, u16* lo, int n){
    k_split<<<(n + 255)/256, 256, 0, stream>>>(src, hi, lo, n);
  };

  // phase 1: enc split + Wa^T split + encWa (fp32)
  split(enc, enc_hi, enc_lo, B_*S_*H_);
  k_waT_split<<<H_, 256, 0, stream>>>(Wa, WaT_hi, WaT_lo);
  k_encWa<<<dim3(128, 16), 256, 0, stream>>>(enc_hi, enc_lo, WaT_hi, WaT_lo, encWa);

  // phase 2: weight splits (overwrite enc_hi/enc_lo region)
  split(Wih0, Wih0_hi, Wih0_lo, 4*H_*XH_);
  split(Whh0, Whh0_hi, Whh0_lo, 4*H_*H_);
  split(Wih1, Wih1_hi, Wih1_lo, 4*H_*H_);
  split(Whh1, Whh1_hi, Whh1_lo, 4*H_*H_);
  hipMemsetAsync(pW_bf + (size_t)V_*H_, 0, (size_t)(VP_ - V_)*H_*2, stream);
  k_f2bf<<<(V_*H_ + 255)/256, 256, 0, stream>>>(pW, pW_bf, V_*H_);
  k_bias<<<16, 256, 0, stream>>>(bih0, bhh0, bias0, 4096);
  k_bias<<<16, 256, 0, stream>>>(bih1, bhh1, bias1, 4096);
  k_emb<<<T_*B_, 256, 0, stream>>>(dec, emb, e_hi, e_lo);
  k_init<<<(2*BH_ + 255)/256, 256, 0, stream>>>(h0i_, c0i_, hst, cst, h0Ah, h0Al, h1Ah, h1Al);

  // phase 3: 128 decode steps
  for (int t = 0; t < T_; t++){
    u16* h0ph = (t & 1) ? h0Bh : h0Ah;  u16* h0pl = (t & 1) ? h0Bl : h0Al;
    u16* h0nh = (t & 1) ? h0Ah : h0Bh;  u16* h0nl = (t & 1) ? h0Al : h0Bl;
    u16* h1ph = (t & 1) ? h1Bh : h1Ah;  u16* h1pl = (t & 1) ? h1Bl : h1Al;
    u16* h1nh = (t & 1) ? h1Ah : h1Bh;  u16* h1nl = (t & 1) ? h1Al : h1Bl;

    k_score<<<512, 512, 0, stream>>>(hst + BH_, encWa, scores);
    k_ctx<<<512, 512, 0, stream>>>(scores, enc, ctxh, ctxl);
    k_gemm<<<512, 512, 0, stream>>>(
        e_hi + (size_t)t*B_*E_, e_lo + (size_t)t*B_*E_, Wih0_hi, Wih0_lo, XH_, E_, E_,
        ctxh, ctxl, Wih0_hi + E_, Wih0_lo + E_, XH_, H_, H_,
        h0ph, h0pl, Whh0_hi, Whh0_lo, H_, H_, H_,
        320, part);
    k_cell<<<512, 128, 0, stream>>>(part, bias0, cst, hst, h0nh, h0nl, (u16*)nullptr);
    k_gemm<<<512, 512, 0, stream>>>(
        h0nh, h0nl, Wih1_hi, Wih1_lo, H_, H_, H_,
        h1ph, h1pl, Whh1_hi, Whh1_lo, H_, H_, H_,
        (const u16*)nullptr, (const u16*)nullptr, (const u16*)nullptr, (const u16*)nullptr, 0, 0, 0,
        256, part);
    k_cell<<<512, 128, 0, stream>>>(part, bias1, cst + BH_, hst + BH_, h1nh, h1nl, h1all + (size_t)t*BH_);
  }

  // phase 4: deferred projection over all 128 steps + final states
  k_proj<<<dim3(128, VP_/64), 256, 0, stream>>>(h1all, pW_bf, pb, out);
  k_final<<<(2*BH_ + 255)/256, 256, 0, stream>>>(hst, cst, out);
}

// Round 7
// 10235.316 us; speedup vs baseline: 3.3330x; 1.0229x over previous
//
#include <hip/hip_runtime.h>
#include <stdint.h>
#include <stddef.h>

#define B_ 64
#define T_ 128
#define S_ 128
#define H_ 1024
#define E_ 512
#define V_ 4000
#define VP_ 4032
#define BH_ (B_*H_)

typedef __attribute__((ext_vector_type(8))) short bf16x8;
typedef __attribute__((ext_vector_type(4))) float f32x4;
typedef unsigned short u16;

__device__ __forceinline__ float bf2f(u16 x){
  union { unsigned int u; float f; } c; c.u = ((unsigned int)x) << 16; return c.f;
}
__device__ __forceinline__ u16 f2bf(float f){
  union { float f; unsigned int u; } c; c.f = f;
  return (u16)((c.u + 0x7FFFu + ((c.u >> 16) & 1u)) >> 16);
}
__device__ __forceinline__ void split2(float x, u16& hi, u16& lo){
  u16 h = f2bf(x); hi = h; lo = f2bf(x - bf2f(h));
}
__device__ __forceinline__ float sigm(float x){ return 1.f/(1.f+__expf(-x)); }
__device__ __forceinline__ float tanh_f(float x){
  float z = __expf(-2.f*fabsf(x));
  float r = (1.f - z)/(1.f + z);
  return x < 0.f ? -r : r;
}

// ---------------- prep kernels ----------------

__global__ __launch_bounds__(256) void k_f2bf(const float* __restrict__ in, u16* __restrict__ out, int n){
  int i = blockIdx.x*256 + threadIdx.x;
  if (i < n) out[i] = f2bf(in[i]);
}

__global__ __launch_bounds__(256) void k_split(const float* __restrict__ in,
                                               u16* __restrict__ hi, u16* __restrict__ lo, int n){
  int i = blockIdx.x*256 + threadIdx.x;
  if (i < n){ u16 a, b; split2(in[i], a, b); hi[i] = a; lo[i] = b; }
}

__global__ __launch_bounds__(256) void k_waT_split(const float* __restrict__ Wa,
                                                   u16* __restrict__ Th, u16* __restrict__ Tl){
  int n = blockIdx.x;
  for (int h = threadIdx.x; h < H_; h += 256){
    u16 a, b; split2(Wa[(size_t)h*H_ + n], a, b);
    Th[(size_t)n*H_ + h] = a; Tl[(size_t)n*H_ + h] = b;
  }
}

__global__ __launch_bounds__(256) void k_bias(const float* __restrict__ a, const float* __restrict__ b,
                                              float* __restrict__ o, int n){
  int i = blockIdx.x*256 + threadIdx.x;
  if (i < n) o[i] = a[i] + b[i];
}

__global__ __launch_bounds__(256) void k_emb(const int* __restrict__ tok, const float* __restrict__ emb,
                                             u16* __restrict__ ehi, u16* __restrict__ elo){
  int bid = blockIdx.x;
  int t = bid >> 6, b = bid & 63;
  int tk = tok[b*T_ + t];
  const float* src = emb + (size_t)tk*E_;
  u16* dh = ehi + (size_t)bid*E_;
  u16* dl = elo + (size_t)bid*E_;
  for (int j = threadIdx.x; j < E_; j += 256){
    if (tk == 0){ dh[j] = 0; dl[j] = 0; }
    else { u16 a, c; split2(src[j], a, c); dh[j] = a; dl[j] = c; }
  }
}

__global__ __launch_bounds__(256) void k_init(const float* __restrict__ h0, const float* __restrict__ c0,
                                              float* __restrict__ hs, float* __restrict__ cs,
                                              u16* __restrict__ h0h, u16* __restrict__ h0l,
                                              u16* __restrict__ h1h, u16* __restrict__ h1l){
  int i = blockIdx.x*256 + threadIdx.x;
  if (i < 2*BH_){ hs[i] = h0[i]; cs[i] = c0[i]; }
  if (i < BH_){
    u16 a, b;
    split2(h0[i], a, b);        h0h[i] = a; h0l[i] = b;
    split2(h0[BH_ + i], a, b);  h1h[i] = a; h1l[i] = b;
  }
}

// encWa[r][n] = sum_h enc[r][h] * Wa[h][n]  (fp32 out via 3-pass hi/lo MFMA) — one-time prep
__global__ __launch_bounds__(256) void k_encWa(const u16* __restrict__ Ah, const u16* __restrict__ Al,
                                               const u16* __restrict__ Bh, const u16* __restrict__ Bl,
                                               float* __restrict__ out){
  int w = threadIdx.x >> 6, lane = threadIdx.x & 63;
  int lm = lane & 15, q = lane >> 4, qo = q*8;
  int m0 = blockIdx.x*64 + w*16;
  int n0 = blockIdx.y*64;
  const u16* arh = Ah + (size_t)(m0 + lm)*H_ + qo;
  const u16* arl = Al + (size_t)(m0 + lm)*H_ + qo;
  const u16* brh[4]; const u16* brl[4];
  #pragma unroll
  for (int nf = 0; nf < 4; nf++){
    brh[nf] = Bh + (size_t)(n0 + nf*16 + lm)*H_ + qo;
    brl[nf] = Bl + (size_t)(n0 + nf*16 + lm)*H_ + qo;
  }
  f32x4 acc[4] = {};
  for (int k = 0; k < H_; k += 32){
    bf16x8 ah = *(const bf16x8*)(arh + k);
    bf16x8 al = *(const bf16x8*)(arl + k);
    #pragma unroll
    for (int nf = 0; nf < 4; nf++){
      bf16x8 bh = *(const bf16x8*)(brh[nf] + k);
      bf16x8 bl = *(const bf16x8*)(brl[nf] + k);
      acc[nf] = __builtin_amdgcn_mfma_f32_16x16x32_bf16(ah, bh, acc[nf], 0, 0, 0);
      acc[nf] = __builtin_amdgcn_mfma_f32_16x16x32_bf16(al, bh, acc[nf], 0, 0, 0);
      acc[nf] = __builtin_amdgcn_mfma_f32_16x16x32_bf16(ah, bl, acc[nf], 0, 0, 0);
    }
  }
  #pragma unroll
  for (int nf = 0; nf < 4; nf++)
    #pragma unroll
    for (int r = 0; r < 4; r++)
      out[(size_t)(m0 + q*4 + r)*H_ + n0 + nf*16 + lm] = acc[nf][r];
}

// ---------------- step kernels ----------------

// 3-pass hi/lo GEMM segment over k in [klo,khi): acc += (x_hi+x_lo)W_hi + x_hi W_lo
__device__ __forceinline__ void seg3(const u16* __restrict__ xh, const u16* __restrict__ xl, int sx,
                                     const u16* __restrict__ wh, const u16* __restrict__ wl,
                                     int lm, int qo, int klo, int khi, f32x4* acc){
  if (klo >= khi) return;
  #pragma unroll 4
  for (int k = klo; k < khi; k += 32){
    bf16x8 vbh = *(const bf16x8*)(wh + k + qo);
    bf16x8 vbl = *(const bf16x8*)(wl + k + qo);
    #pragma unroll
    for (int m = 0; m < 4; m++){
      bf16x8 vah = *(const bf16x8*)(xh + (size_t)(m*16 + lm)*sx + k + qo);
      bf16x8 val = *(const bf16x8*)(xl + (size_t)(m*16 + lm)*sx + k + qo);
      acc[m] = __builtin_amdgcn_mfma_f32_16x16x32_bf16(vah, vbh, acc[m], 0, 0, 0);
      acc[m] = __builtin_amdgcn_mfma_f32_16x16x32_bf16(val, vbh, acc[m], 0, 0, 0);
      acc[m] = __builtin_amdgcn_mfma_f32_16x16x32_bf16(vah, vbl, acc[m], 0, 0, 0);
    }
  }
}

// K1: packed dispatch.
// bid<256: gemmA block (j,g): gates0[b][n] = e·Wih0[:, :512] + h0·Whh0   (overwrite)
// bid>=256: attn block b: cell1(t-1) [if gates1] -> h1 in LDS -> scores -> softmax -> ctx
__global__ __launch_bounds__(512, 4) void k_step1(
    const u16* __restrict__ e_hi, const u16* __restrict__ e_lo,
    const u16* __restrict__ Wih0_hi, const u16* __restrict__ Wih0_lo,
    const u16* __restrict__ h0h, const u16* __restrict__ h0l,
    const u16* __restrict__ Whh0_hi, const u16* __restrict__ Whh0_lo,
    float* __restrict__ gates0,
    const float* __restrict__ gates1, const float* __restrict__ bias1,
    float* __restrict__ cst1, const float* __restrict__ h1init,
    const float* __restrict__ encWa, const float* __restrict__ enc,
    u16* __restrict__ h1h, u16* __restrict__ h1l, u16* __restrict__ h1all_prev,
    u16* __restrict__ ctxh, u16* __restrict__ ctxl){
  __shared__ float L[8*64*16];   // 32 KB, shared by both paths
  int bid = blockIdx.x, tid = threadIdx.x;
  if (bid < 256){
    int j = bid & 63, g = bid >> 6;
    int w = tid >> 6, lane = tid & 63;
    int lm = lane & 15, q = lane >> 4, qo = q*8;
    int n = g*H_ + j*16 + lm;
    int c0 = w*192, c1 = c0 + 192;       // K = 512(e) + 1024(h0) = 1536
    f32x4 acc[4] = {};
    {
      int hi = (c1 < 512) ? c1 : 512;
      seg3(e_hi, e_lo, 512, Wih0_hi + (size_t)n*1536, Wih0_lo + (size_t)n*1536, lm, qo, c0, hi, acc);
    }
    {
      int lo = c0 - 512; if (lo < 0) lo = 0;
      int hi = c1 - 512; if (hi > 1024) hi = 1024;
      seg3(h0h, h0l, 1024, Whh0_hi + (size_t)n*1024, Whh0_lo + (size_t)n*1024, lm, qo, lo, hi, acc);
    }
    float (*smg)[64][16] = (float(*)[64][16])L;
    #pragma unroll
    for (int m = 0; m < 4; m++)
      #pragma unroll
      for (int r = 0; r < 4; r++)
        smg[w][m*16 + q*4 + r][lm] = acc[m][r];
    __syncthreads();
    #pragma unroll
    for (int p = tid; p < 1024; p += 512){
      int b = p >> 4, dd = p & 15;
      float s = 0.f;
      #pragma unroll
      for (int ww = 0; ww < 8; ww++) s += smg[ww][b][dd];
      gates0[(size_t)b*4096 + g*H_ + j*16 + dd] = s;
    }
  } else {
    int b = bid - 256;
    float* smh = L;          // [1024] h1 row
    float* smp = L + 1024;   // [128] scores
    // phase 0: cell1(t-1) (or load initial h1)
    for (int p = tid; p < 1024; p += 512){
      float hv;
      if (gates1){
        const float* gb = gates1 + (size_t)b*4096;
        float gi = gb[p]        + bias1[p];
        float gf = gb[1024 + p] + bias1[1024 + p];
        float gg = gb[2048 + p] + bias1[2048 + p];
        float go = gb[3072 + p] + bias1[3072 + p];
        size_t sidx = (size_t)b*H_ + p;
        float cn = sigm(gf)*cst1[sidx] + sigm(gi)*tanh_f(gg);
        hv = sigm(go)*tanh_f(cn);
        cst1[sidx] = cn;
        u16 hh, hl; split2(hv, hh, hl);
        h1h[sidx] = hh; h1l[sidx] = hl;
        h1all_prev[sidx] = hh;
      } else {
        hv = h1init[(size_t)b*H_ + p];
      }
      smh[p] = hv;
    }
    __syncthreads();
    // phase 1: scores — 8 waves x 16 s
    int w = tid >> 6, lane = tid & 63;
    float hf[16];
    #pragma unroll
    for (int jj = 0; jj < 16; jj += 4){
      float4 v = *(const float4*)(smh + lane*16 + jj);
      hf[jj] = v.x; hf[jj+1] = v.y; hf[jj+2] = v.z; hf[jj+3] = v.w;
    }
    #pragma unroll 4
    for (int si = 0; si < 16; si++){
      int s = w*16 + si;
      const float* er = encWa + ((size_t)b*S_ + s)*H_ + lane*16;
      float acc = 0.f;
      #pragma unroll
      for (int jj = 0; jj < 16; jj += 4){
        float4 v = *(const float4*)(er + jj);
        acc += hf[jj]*v.x + hf[jj+1]*v.y + hf[jj+2]*v.z + hf[jj+3]*v.w;
      }
      #pragma unroll
      for (int off = 32; off; off >>= 1) acc += __shfl_xor(acc, off, 64);
      if (lane == 0) smp[s] = acc;
    }
    __syncthreads();
    // phase 2: softmax (redundant per thread)
    float mx = -1e30f;
    #pragma unroll 8
    for (int s = 0; s < S_; s++) mx = fmaxf(mx, smp[s]);
    __syncthreads();
    if (tid < S_) smp[tid] = __expf(smp[tid] - mx);
    __syncthreads();
    float sum = 0.f;
    #pragma unroll 8
    for (int s = 0; s < S_; s++) sum += smp[s];
    float inv = 1.f/sum;
    // phase 3: ctx — thread owns 2 dims
    int d0 = tid*2;
    const float* eb = enc + ((size_t)b*S_)*H_ + d0;
    float a0 = 0.f, a1 = 0.f;
    #pragma unroll 8
    for (int s = 0; s < S_; s++){
      float pv = smp[s];
      float2 ev = *(const float2*)(eb + (size_t)s*H_);
      a0 += pv*ev.x; a1 += pv*ev.y;
    }
    int o = b*H_ + d0;
    u16 hh, hl;
    split2(a0*inv, hh, hl); ctxh[o]   = hh; ctxl[o]   = hl;
    split2(a1*inv, hh, hl); ctxh[o+1] = hh; ctxl[o+1] = hl;
  }
}

// K2: gates0 += ctx·Wih0[:, 512:1536].  grid 256 = (j,g), 8 waves = 8 K-slices of 128.
__global__ __launch_bounds__(512, 4) void k_gemmB(
    const u16* __restrict__ ctxh, const u16* __restrict__ ctxl,
    const u16* __restrict__ Wih0_hi, const u16* __restrict__ Wih0_lo,
    float* __restrict__ gates0){
  __shared__ float L[8*64*16];
  int j = blockIdx.x & 63, g = blockIdx.x >> 6;
  int tid = threadIdx.x;
  int w = tid >> 6, lane = tid & 63;
  int lm = lane & 15, q = lane >> 4, qo = q*8;
  int n = g*H_ + j*16 + lm;
  f32x4 acc[4] = {};
  seg3(ctxh, ctxl, 1024, Wih0_hi + (size_t)n*1536 + 512, Wih0_lo + (size_t)n*1536 + 512,
       lm, qo, w*128, w*128 + 128, acc);
  float (*smg)[64][16] = (float(*)[64][16])L;
  #pragma unroll
  for (int m = 0; m < 4; m++)
    #pragma unroll
    for (int r = 0; r < 4; r++)
      smg[w][m*16 + q*4 + r][lm] = acc[m][r];
  __syncthreads();
  #pragma unroll
  for (int p = tid; p < 1024; p += 512){
    int b = p >> 4, dd = p & 15;
    float s = 0.f;
    #pragma unroll
    for (int ww = 0; ww < 8; ww++) s += smg[ww][b][dd];
    size_t idx = (size_t)b*4096 + g*H_ + j*16 + dd;
    gates0[idx] += s;
  }
}

// K3: cell update layer 0. grid 128 x 512.
__global__ __launch_bounds__(512) void k_cell0(const float* __restrict__ gates, const float* __restrict__ bias,
                                               float* __restrict__ cst, float* __restrict__ hst,
                                               u16* __restrict__ hnh, u16* __restrict__ hnl){
  int idx = blockIdx.x*512 + threadIdx.x;
  int d = idx & 1023, b = idx >> 10;
  const float* gb = gates + (size_t)b*4096;
  float gi = gb[d]        + bias[d];
  float gf = gb[1024 + d] + bias[1024 + d];
  float gg = gb[2048 + d] + bias[2048 + d];
  float go = gb[3072 + d] + bias[3072 + d];
  size_t sidx = (size_t)b*H_ + d;
  float cn = sigm(gf)*cst[sidx] + sigm(gi)*tanh_f(gg);
  float hn = sigm(go)*tanh_f(cn);
  cst[sidx] = cn; hst[sidx] = hn;
  u16 hh, hl; split2(hn, hh, hl);
  hnh[sidx] = hh; hnl[sidx] = hl;
}

// K4: gates1 = h0n·Wih1 + h1p·Whh1. grid 256 = (j,g), 8 waves = 8 K-slices of 256 over K=2048.
__global__ __launch_bounds__(512, 4) void k_gemm1(
    const u16* __restrict__ x1h, const u16* __restrict__ x1l,
    const u16* __restrict__ W1h, const u16* __restrict__ W1l,
    const u16* __restrict__ x2h, const u16* __restrict__ x2l,
    const u16* __restrict__ W2h, const u16* __restrict__ W2l,
    float* __restrict__ gates1){
  __shared__ float L[8*64*16];
  int j = blockIdx.x & 63, g = blockIdx.x >> 6;
  int tid = threadIdx.x;
  int w = tid >> 6, lane = tid & 63;
  int lm = lane & 15, q = lane >> 4, qo = q*8;
  int n = g*H_ + j*16 + lm;
  int c0 = w*256, c1 = c0 + 256;
  f32x4 acc[4] = {};
  {
    int hi = (c1 < 1024) ? c1 : 1024;
    seg3(x1h, x1l, 1024, W1h + (size_t)n*1024, W1l + (size_t)n*1024, lm, qo, c0, hi, acc);
  }
  {
    int lo = c0 - 1024; if (lo < 0) lo = 0;
    int hi = c1 - 1024; if (hi > 1024) hi = 1024;
    seg3(x2h, x2l, 1024, W2h + (size_t)n*1024, W2l + (size_t)n*1024, lm, qo, lo, hi, acc);
  }
  float (*smg)[64][16] = (float(*)[64][16])L;
  #pragma unroll
  for (int m = 0; m < 4; m++)
    #pragma unroll
    for (int r = 0; r < 4; r++)
      smg[w][m*16 + q*4 + r][lm] = acc[m][r];
  __syncthreads();
  #pragma unroll
  for (int p = tid; p < 1024; p += 512){
    int b = p >> 4, dd = p & 15;
    float s = 0.f;
    #pragma unroll
    for (int ww = 0; ww < 8; ww++) s += smg[ww][b][dd];
    gates1[(size_t)b*4096 + g*H_ + j*16 + dd] = s;
  }
}

// trailing cell1 for t = T-1: final states + h1all[127]
__global__ __launch_bounds__(512) void k_cellF(const float* __restrict__ gates, const float* __restrict__ bias,
                                               float* __restrict__ cst, float* __restrict__ hst,
                                               u16* __restrict__ hall){
  int idx = blockIdx.x*512 + threadIdx.x;
  int d = idx & 1023, b = idx >> 10;
  const float* gb = gates + (size_t)b*4096;
  float gi = gb[d]        + bias[d];
  float gf = gb[1024 + d] + bias[1024 + d];
  float gg = gb[2048 + d] + bias[2048 + d];
  float go = gb[3072 + d] + bias[3072 + d];
  size_t sidx = (size_t)b*H_ + d;
  float cn = sigm(gf)*cst[sidx] + sigm(gi)*tanh_f(gg);
  float hn = sigm(go)*tanh_f(cn);
  cst[sidx] = cn; hst[sidx] = hn;
  hall[sidx] = f2bf(hn);
}

// ---------------- final projection + state copy ----------------

__global__ __launch_bounds__(256) void k_proj(const u16* __restrict__ h1all, const u16* __restrict__ Wp,
                                              const float* __restrict__ pb, float* __restrict__ out){
  int w = threadIdx.x >> 6, lane = threadIdx.x & 63;
  int lm = lane & 15, q = lane >> 4, qo = q*8;
  int m0 = blockIdx.x*64 + w*16;
  int n0 = blockIdx.y*64;
  const u16* arow = h1all + (size_t)(m0 + lm)*H_ + qo;
  const u16* brow[4];
  #pragma unroll
  for (int nf = 0; nf < 4; nf++) brow[nf] = Wp + (size_t)(n0 + nf*16 + lm)*H_ + qo;
  f32x4 acc[4] = {};
  for (int k = 0; k < H_; k += 32){
    bf16x8 a = *(const bf16x8*)(arow + k);
    #pragma unroll
    for (int nf = 0; nf < 4; nf++){
      bf16x8 bb = *(const bf16x8*)(brow[nf] + k);
      acc[nf] = __builtin_amdgcn_mfma_f32_16x16x32_bf16(a, bb, acc[nf], 0, 0, 0);
    }
  }
  #pragma unroll
  for (int nf = 0; nf < 4; nf++){
    int v = n0 + nf*16 + lm;
    if (v >= V_) continue;
    float bias = pb[v];
    #pragma unroll
    for (int r = 0; r < 4; r++){
      int row = m0 + q*4 + r;           // row = t*64 + b
      int t = row >> 6, b = row & 63;
      out[((size_t)b*T_ + t)*V_ + v] = acc[nf][r] + bias;
    }
  }
}

__global__ __launch_bounds__(256) void k_final(const float* __restrict__ hs, const float* __restrict__ cs,
                                               float* __restrict__ out){
  size_t LOG = (size_t)B_*T_*V_;
  int i = blockIdx.x*256 + threadIdx.x;
  if (i < 2*BH_){
    out[LOG + i] = hs[i];
    out[LOG + 2*BH_ + i] = cs[i];
  }
}

// ---------------- launch ----------------

extern "C" void kernel_launch(void* const* d_in, const int* in_sizes, int n_in,
                              void* d_out, int out_size, void* d_ws, size_t ws_size,
                              hipStream_t stream){
  (void)in_sizes; (void)n_in; (void)out_size; (void)ws_size;
  const int*   dec  = (const int*)  d_in[0];
  const float* enc  = (const float*)d_in[1];
  const float* h0i_ = (const float*)d_in[3];
  const float* c0i_ = (const float*)d_in[4];
  const float* emb  = (const float*)d_in[5];
  const float* Wa   = (const float*)d_in[6];
  const float* Wih0 = (const float*)d_in[7];
  const float* Whh0 = (const float*)d_in[8];
  const float* bih0 = (const float*)d_in[9];
  const float* bhh0 = (const float*)d_in[10];
  const float* Wih1 = (const float*)d_in[11];
  const float* Whh1 = (const float*)d_in[12];
  const float* bih1 = (const float*)d_in[13];
  const float* bhh1 = (const float*)d_in[14];
  const float* pW   = (const float*)d_in[15];
  const float* pb   = (const float*)d_in[16];
  float* out = (float*)d_out;

  // Scratch carved from the dead logits region of d_out (125 MiB, overwritten by k_proj at end).
  char* db = (char*)d_out;
  float* encWa  = (float*)(db);                    // 33,554,432
  u16* e_hi     = (u16*)(db + 33554432);           //  8,388,608
  u16* e_lo     = (u16*)(db + 41943040);           //  8,388,608 -> 50,331,648
  // transient (dead after k_encWa, then overwritten by weight splits):
  u16* enc_hi   = (u16*)(db + 50331648);           // 16,777,216
  u16* enc_lo   = (u16*)(db + 67108864);           // 16,777,216 -> 83,886,080
  // weights hi+lo (written after k_encWa; stream-ordered):
  u16* Wih0_hi  = (u16*)(db + 50331648);           // 12,582,912 -> 62,914,560
  u16* Wih0_lo  = (u16*)(db + 62914560);           // 12,582,912 -> 75,497,472
  u16* Whh0_hi  = (u16*)(db + 75497472);           //  8,388,608 -> 83,886,080
  u16* Whh0_lo  = (u16*)(db + 83886080);           //  8,388,608 -> 92,274,688
  u16* Wih1_hi  = (u16*)(db + 92274688);           //  8,388,608 -> 100,663,296
  u16* Wih1_lo  = (u16*)(db + 100663296);          //  8,388,608 -> 109,051,904
  u16* Whh1_hi  = (u16*)(db + 109051904);          //  8,388,608 -> 117,440,512
  u16* Whh1_lo  = (u16*)(db + 117440512);          //  8,388,608 -> 125,829,120 (<131,072,000)

  char* ws = (char*)d_ws;
  size_t off = 0;
  auto alloc = [&](size_t bytes)->void*{ void* p = ws + off; off = (off + bytes + 255) & ~(size_t)255; return p; };
  u16* WaT_hi  = (u16*)alloc((size_t)H_*H_*2);
  u16* WaT_lo  = (u16*)alloc((size_t)H_*H_*2);
  u16* pW_bf   = (u16*)alloc((size_t)VP_*H_*2);
  u16* h1all   = (u16*)alloc((size_t)T_*B_*H_*2);
  float* hst   = (float*)alloc((size_t)2*BH_*4);
  float* cst   = (float*)alloc((size_t)2*BH_*4);
  u16* h0h = (u16*)alloc((size_t)BH_*2);  u16* h0l = (u16*)alloc((size_t)BH_*2);
  u16* h1h = (u16*)alloc((size_t)BH_*2);  u16* h1l = (u16*)alloc((size_t)BH_*2);
  u16* ctxh = (u16*)alloc((size_t)BH_*2); u16* ctxl = (u16*)alloc((size_t)BH_*2);
  float* bias0  = (float*)alloc(4096*4);
  float* bias1  = (float*)alloc(4096*4);
  float* gates0 = (float*)alloc((size_t)B_*4096*4);
  float* gates1 = (float*)alloc((size_t)B_*4096*4);

  // phase 1: enc split + Wa^T split + encWa (fp32, full precision — one-time)
  k_split<<<(B_*S_*H_ + 255)/256, 256, 0, stream>>>(enc, enc_hi, enc_lo, B_*S_*H_);
  k_waT_split<<<H_, 256, 0, stream>>>(Wa, WaT_hi, WaT_lo);
  k_encWa<<<dim3(128, 16), 256, 0, stream>>>(enc_hi, enc_lo, WaT_hi, WaT_lo, encWa);

  // phase 2: weight hi/lo splits (overwrite enc_hi/enc_lo region) + misc
  k_split<<<(4*H_*1536 + 255)/256, 256, 0, stream>>>(Wih0, Wih0_hi, Wih0_lo, 4*H_*1536);
  k_split<<<(4*H_*H_ + 255)/256, 256, 0, stream>>>(Whh0, Whh0_hi, Whh0_lo, 4*H_*H_);
  k_split<<<(4*H_*H_ + 255)/256, 256, 0, stream>>>(Wih1, Wih1_hi, Wih1_lo, 4*H_*H_);
  k_split<<<(4*H_*H_ + 255)/256, 256, 0, stream>>>(Whh1, Whh1_hi, Whh1_lo, 4*H_*H_);
  hipMemsetAsync(pW_bf + (size_t)V_*H_, 0, (size_t)(VP_ - V_)*H_*2, stream);
  k_f2bf<<<(V_*H_ + 255)/256, 256, 0, stream>>>(pW, pW_bf, V_*H_);
  k_bias<<<16, 256, 0, stream>>>(bih0, bhh0, bias0, 4096);
  k_bias<<<16, 256, 0, stream>>>(bih1, bhh1, bias1, 4096);
  k_emb<<<T_*B_, 256, 0, stream>>>(dec, emb, e_hi, e_lo);
  k_init<<<(2*BH_ + 255)/256, 256, 0, stream>>>(h0i_, c0i_, hst, cst, h0h, h0l, h1h, h1l);

  // phase 3: 128 decode steps, 4 dispatches each
  for (int t = 0; t < T_; t++){
    k_step1<<<320, 512, 0, stream>>>(
        e_hi + (size_t)t*B_*E_, e_lo + (size_t)t*B_*E_,
        Wih0_hi, Wih0_lo, h0h, h0l, Whh0_hi, Whh0_lo, gates0,
        (t ? gates1 : (const float*)nullptr), bias1, cst + BH_, hst + BH_,
        encWa, enc, h1h, h1l,
        (t ? h1all + (size_t)(t-1)*BH_ : (u16*)nullptr),
        ctxh, ctxl);
    k_gemmB<<<256, 512, 0, stream>>>(ctxh, ctxl, Wih0_hi, Wih0_lo, gates0);
    k_cell0<<<128, 512, 0, stream>>>(gates0, bias0, cst, hst, h0h, h0l);
    k_gemm1<<<256, 512, 0, stream>>>(h0h, h0l, Wih1_hi, Wih1_lo, h1h, h1l, Whh1_hi, Whh1_lo, gates1);
  }
  k_cellF<<<128, 512, 0, stream>>>(gates1, bias1, cst + BH_, hst + BH_, h1all + (size_t)(T_-1)*BH_);

  // phase 4: deferred projection over all 128 steps + final states
  k_proj<<<dim3(128, VP_/64), 256, 0, stream>>>(h1all, pW_bf, pb, out);
  k_final<<<(2*BH_ + 255)/256, 256, 0, stream>>>(hst, cst, out);
}